// Round 3
// baseline (177.250 us; speedup 1.0000x reference)
//
#include <hip/hip_runtime.h>
#include <stdint.h>

// Problem constants (B,C,D,H,W) = (2,1,128,256,256)
#define BB 2
#define DD 128
#define HH 256
#define WW 256
static constexpr int64_t N = (int64_t)BB * DD * HH * WW;   // 16,777,216
static constexpr int WPR    = WW / 64;                     // 4 words per row
static constexpr int NWORDS = BB * DD * HH * WPR;          // 262,144 words (2 MB)
static constexpr int ZSTR   = HH * WPR;                    // 1024 words per z-plane
static constexpr int RBLOCKS = 4096;                       // reduce grid

// ---------------------------------------------------------------------------
// K1: predicate + X-dilation (radius 3), bit-packed via __ballot.
// One wave = one W-row (256 voxels). Lane l loads t[row*256 + 64k + l],
// ballot of the predicate IS packed word k. X-dilation is wave-uniform
// scalar 64-bit shift/OR. No LDS, no __syncthreads.
// ---------------------------------------------------------------------------
__global__ __launch_bounds__(256) void mask_xdil(const float* __restrict__ tgt,
                                                 uint64_t* __restrict__ mask) {
    const int wave = threadIdx.x >> 6;
    const int lane = threadIdx.x & 63;
    const int row  = blockIdx.x * 4 + wave;             // 65,536 rows total
    const float* p = tgt + (int64_t)row * WW + lane;

    uint64_t w[4];
    #pragma unroll
    for (int k = 0; k < 4; k++) {
        float t = p[k * 64];
        w[k] = __ballot(t > 0.0f && t < 1.0f);
    }

    uint64_t d[4];
    #pragma unroll
    for (int k = 0; k < 4; k++) {
        const uint64_t C = w[k];
        const uint64_t L = (k > 0) ? w[k - 1] : 0ull;
        const uint64_t R = (k < 3) ? w[k + 1] : 0ull;
        uint64_t v = C;
        #pragma unroll
        for (int s = 1; s <= 3; s++) {
            v |= (C << s) | (C >> s);
            v |= L >> (64 - s);
            v |= R << (64 - s);
        }
        d[k] = v;
    }

    if (lane < 4) {
        uint64_t v = d[0];
        if (lane == 1) v = d[1];
        if (lane == 2) v = d[2];
        if (lane == 3) v = d[3];
        mask[(int64_t)row * WPR + lane] = v;
    }
}

// ---------------------------------------------------------------------------
// K2a: Y dilation (radius 3). 7 fully-unrolled predicated loads per word.
// ---------------------------------------------------------------------------
__global__ __launch_bounds__(256) void y_dil(const uint64_t* __restrict__ in,
                                             uint64_t* __restrict__ out) {
    const int n = blockIdx.x * 256 + threadIdx.x;
    const int y = (n >> 2) & (HH - 1);
    uint64_t acc = 0;
    #pragma unroll
    for (int dy = -3; dy <= 3; dy++) {
        const int yy = y + dy;
        acc |= (yy >= 0 && yy < HH) ? in[n + dy * WPR] : 0ull;
    }
    out[n] = acc;
}

// ---------------------------------------------------------------------------
// K2b: Z dilation (radius 3). 7 fully-unrolled predicated loads per word.
// ---------------------------------------------------------------------------
__global__ __launch_bounds__(256) void z_dil(const uint64_t* __restrict__ in,
                                             uint64_t* __restrict__ out) {
    const int n = blockIdx.x * 256 + threadIdx.x;
    const int z = (n >> 10) & (DD - 1);
    uint64_t acc = 0;
    #pragma unroll
    for (int dz = -3; dz <= 3; dz++) {
        const int zz = z + dz;
        acc |= (zz >= 0 && zz < DD) ? in[n + dz * ZSTR] : 0ull;
    }
    out[n] = acc;
}

// ---------------------------------------------------------------------------
// K3: weighted L1 partial reduction. float4 loads, mask nibble per float4,
// wave shuffle -> LDS -> ONE non-atomic double store per block.
// ---------------------------------------------------------------------------
__global__ __launch_bounds__(256) void reduce_loss(const float* __restrict__ inp,
                                                   const float* __restrict__ tgt,
                                                   const uint64_t* __restrict__ mask,
                                                   double* __restrict__ partials) {
    const int64_t nvec = N / 4;
    const int64_t stride = (int64_t)RBLOCKS * 256;
    float local = 0.0f;
    for (int64_t i = (int64_t)blockIdx.x * 256 + threadIdx.x; i < nvec; i += stride) {
        float4 a = ((const float4*)inp)[i];
        float4 t = ((const float4*)tgt)[i];
        uint64_t w = mask[i >> 4];
        unsigned nib = (unsigned)(w >> ((i & 15) * 4)) & 0xFu;
        float s;
        s  = fabsf(t.x - a.x) * ((nib & 1u) ? 11.0f : 1.0f);
        s += fabsf(t.y - a.y) * ((nib & 2u) ? 11.0f : 1.0f);
        s += fabsf(t.z - a.z) * ((nib & 4u) ? 11.0f : 1.0f);
        s += fabsf(t.w - a.w) * ((nib & 8u) ? 11.0f : 1.0f);
        local += s;
    }
    #pragma unroll
    for (int off = 32; off > 0; off >>= 1)
        local += __shfl_down(local, off, 64);
    __shared__ float wsum[4];
    const int lane = threadIdx.x & 63;
    const int wv   = threadIdx.x >> 6;
    if (lane == 0) wsum[wv] = local;
    __syncthreads();
    if (threadIdx.x == 0)
        partials[blockIdx.x] = (double)(wsum[0] + wsum[1] + wsum[2] + wsum[3]);
}

// ---------------------------------------------------------------------------
// K4: sum 4096 double partials, divide by N.
// ---------------------------------------------------------------------------
__global__ __launch_bounds__(1024) void finalize(const double* __restrict__ partials,
                                                 float* __restrict__ out) {
    double local = 0.0;
    for (int i = threadIdx.x; i < RBLOCKS; i += 1024) local += partials[i];
    #pragma unroll
    for (int off = 32; off > 0; off >>= 1)
        local += __shfl_down(local, off, 64);
    __shared__ double ws[16];
    const int lane = threadIdx.x & 63;
    const int wv   = threadIdx.x >> 6;
    if (lane == 0) ws[wv] = local;
    __syncthreads();
    if (threadIdx.x == 0) {
        double s = 0.0;
        #pragma unroll
        for (int k = 0; k < 16; k++) s += ws[k];
        out[0] = (float)(s / (double)N);
    }
}

extern "C" void kernel_launch(void* const* d_in, const int* in_sizes, int n_in,
                              void* d_out, int out_size, void* d_ws, size_t ws_size,
                              hipStream_t stream) {
    const float* inp = (const float*)d_in[0];   // "input"
    const float* tgt = (const float*)d_in[1];   // "target"
    float* out = (float*)d_out;

    double*   partials = (double*)d_ws;                        // 32 KB (fully written)
    uint64_t* mask0 = (uint64_t*)((char*)d_ws + 64 * 1024);    // 2 MB
    uint64_t* mask1 = mask0 + NWORDS;                          // 2 MB

    mask_xdil<<<NWORDS / 16, 256, 0, stream>>>(tgt, mask0);    // 16384 blocks, 4 rows each
    y_dil<<<NWORDS / 256, 256, 0, stream>>>(mask0, mask1);
    z_dil<<<NWORDS / 256, 256, 0, stream>>>(mask1, mask0);
    reduce_loss<<<RBLOCKS, 256, 0, stream>>>(inp, tgt, mask0, partials);
    finalize<<<1, 1024, 0, stream>>>(partials, out);
}

// Round 4
// 151.463 us; speedup vs baseline: 1.1703x; 1.1703x over previous
//
#include <hip/hip_runtime.h>
#include <stdint.h>

// Problem constants (B,C,D,H,W) = (2,1,128,256,256)
#define BB 2
#define DD 128
#define HH 256
#define WW 256
static constexpr int64_t N = (int64_t)BB * DD * HH * WW;   // 16,777,216
static constexpr int WPR    = WW / 64;                     // 4 words per row
static constexpr int NWORDS = BB * DD * HH * WPR;          // 262,144 words (2 MB)
static constexpr int RBLOCKS = 4096;                       // reduce grid

__device__ __forceinline__ uint64_t shfl_xor_u64(uint64_t v, int lanemask) {
    int lo = __shfl_xor((int)(uint32_t)v, lanemask, 64);
    int hi = __shfl_xor((int)(v >> 32), lanemask, 64);
    return ((uint64_t)(uint32_t)hi << 32) | (uint32_t)lo;
}

// ---------------------------------------------------------------------------
// K1: predicate + X-dilation (radius 3), bit-packed. One wave = one W-row.
// Lane l loads float4 l of the row (voxels 4l..4l+3) -> nibble. X-dilation
// via 12-bit window from lane+-1 nibbles (shfl, edges zeroed). Pack 16
// nibbles/uint64 with a shfl_xor butterfly. No LDS, no syncthreads.
// ---------------------------------------------------------------------------
__global__ __launch_bounds__(256) void mask_xdil(const float* __restrict__ tgt,
                                                 uint64_t* __restrict__ mask) {
    const int wave = threadIdx.x >> 6;
    const int lane = threadIdx.x & 63;
    const int row  = blockIdx.x * 4 + wave;             // 65,536 rows total

    float4 t = ((const float4*)(tgt + (int64_t)row * WW))[lane];
    unsigned nib = 0;
    nib |= (t.x > 0.0f && t.x < 1.0f) ? 1u : 0u;
    nib |= (t.y > 0.0f && t.y < 1.0f) ? 2u : 0u;
    nib |= (t.z > 0.0f && t.z < 1.0f) ? 4u : 0u;
    nib |= (t.w > 0.0f && t.w < 1.0f) ? 8u : 0u;

    unsigned L = (unsigned)__shfl_up((int)nib, 1, 64);
    unsigned R = (unsigned)__shfl_down((int)nib, 1, 64);
    if (lane == 0)  L = 0;
    if (lane == 63) R = 0;

    // 12-bit window: bit b <-> voxel 4l-4+b. Own voxel j is at b=4+j;
    // dilation radius 3 -> OR of window bits [j+1, j+7].
    const unsigned m = L | (nib << 4) | (R << 8);
    unsigned dil = 0;
    #pragma unroll
    for (int j = 0; j < 4; j++)
        dil |= ((m & (0x7Fu << (j + 1))) ? 1u : 0u) << j;

    // butterfly pack: after step s, each lane group of 2^(s+1) holds the
    // concatenated nibbles of the group (low lane = low bits).
    uint64_t x = dil;
    #pragma unroll
    for (int s = 0; s < 4; s++) {
        const int sh = 4 << s;                 // 4, 8, 16, 32
        uint64_t p = shfl_xor_u64(x, 1 << s);
        x = (lane & (1 << s)) ? (p | (x << sh)) : (x | (p << sh));
    }
    if ((lane & 15) == 0)
        mask[(int64_t)row * WPR + (lane >> 4)] = x;
}

// ---------------------------------------------------------------------------
// K2: fused Y+Z dilation (radius 3 each) on the packed mask, LDS-tiled.
// Block = 16x16 (y,z) output tile for fixed (b,wx). Raw 22x22 halo tile ->
// y-dilate into yd[22][16] -> z-dilate -> store. 2MB read + 2MB write total.
// ---------------------------------------------------------------------------
__global__ __launch_bounds__(256) void yz_dil(const uint64_t* __restrict__ in,
                                              uint64_t* __restrict__ out) {
    __shared__ uint64_t raw[22][23];   // +1 pad
    __shared__ uint64_t yd[22][17];    // +1 pad
    const int ty = threadIdx.x & 15;
    const int tz = threadIdx.x >> 4;
    const int y0 = blockIdx.x * 16;
    const int z0 = blockIdx.y * 16;
    const int b  = blockIdx.z >> 2;
    const int wx = blockIdx.z & 3;

    for (int idx = threadIdx.x; idx < 22 * 22; idx += 256) {
        const int zz = idx / 22, yy = idx % 22;
        const int gz = z0 - 3 + zz, gy = y0 - 3 + yy;
        uint64_t v = 0;
        if (gz >= 0 && gz < DD && gy >= 0 && gy < HH)
            v = in[(((int64_t)(b * DD + gz)) * HH + gy) * WPR + wx];
        raw[zz][yy] = v;
    }
    __syncthreads();

    for (int idx = threadIdx.x; idx < 22 * 16; idx += 256) {
        const int zz = idx >> 4, yy = idx & 15;
        uint64_t v = 0;
        #pragma unroll
        for (int d = 0; d < 7; d++) v |= raw[zz][yy + d];
        yd[zz][yy] = v;
    }
    __syncthreads();

    uint64_t v = 0;
    #pragma unroll
    for (int d = 0; d < 7; d++) v |= yd[tz + d][ty];
    out[(((int64_t)(b * DD + z0 + tz)) * HH + y0 + ty) * WPR + wx] = v;
}

// ---------------------------------------------------------------------------
// K3: weighted L1 partial reduction. float4 loads, mask nibble per float4,
// wave shuffle -> LDS -> ONE non-atomic double store per block.
// ---------------------------------------------------------------------------
__global__ __launch_bounds__(256) void reduce_loss(const float* __restrict__ inp,
                                                   const float* __restrict__ tgt,
                                                   const uint64_t* __restrict__ mask,
                                                   double* __restrict__ partials) {
    const int64_t nvec = N / 4;
    const int64_t stride = (int64_t)RBLOCKS * 256;
    float local = 0.0f;
    for (int64_t i = (int64_t)blockIdx.x * 256 + threadIdx.x; i < nvec; i += stride) {
        float4 a = ((const float4*)inp)[i];
        float4 t = ((const float4*)tgt)[i];
        uint64_t w = mask[i >> 4];
        unsigned nib = (unsigned)(w >> ((i & 15) * 4)) & 0xFu;
        float s;
        s  = fabsf(t.x - a.x) * ((nib & 1u) ? 11.0f : 1.0f);
        s += fabsf(t.y - a.y) * ((nib & 2u) ? 11.0f : 1.0f);
        s += fabsf(t.z - a.z) * ((nib & 4u) ? 11.0f : 1.0f);
        s += fabsf(t.w - a.w) * ((nib & 8u) ? 11.0f : 1.0f);
        local += s;
    }
    #pragma unroll
    for (int off = 32; off > 0; off >>= 1)
        local += __shfl_down(local, off, 64);
    __shared__ float wsum[4];
    const int lane = threadIdx.x & 63;
    const int wv   = threadIdx.x >> 6;
    if (lane == 0) wsum[wv] = local;
    __syncthreads();
    if (threadIdx.x == 0)
        partials[blockIdx.x] = (double)(wsum[0] + wsum[1] + wsum[2] + wsum[3]);
}

// ---------------------------------------------------------------------------
// K4: sum 4096 double partials, divide by N.
// ---------------------------------------------------------------------------
__global__ __launch_bounds__(1024) void finalize(const double* __restrict__ partials,
                                                 float* __restrict__ out) {
    double local = 0.0;
    for (int i = threadIdx.x; i < RBLOCKS; i += 1024) local += partials[i];
    #pragma unroll
    for (int off = 32; off > 0; off >>= 1)
        local += __shfl_down(local, off, 64);
    __shared__ double ws[16];
    const int lane = threadIdx.x & 63;
    const int wv   = threadIdx.x >> 6;
    if (lane == 0) ws[wv] = local;
    __syncthreads();
    if (threadIdx.x == 0) {
        double s = 0.0;
        #pragma unroll
        for (int k = 0; k < 16; k++) s += ws[k];
        out[0] = (float)(s / (double)N);
    }
}

extern "C" void kernel_launch(void* const* d_in, const int* in_sizes, int n_in,
                              void* d_out, int out_size, void* d_ws, size_t ws_size,
                              hipStream_t stream) {
    const float* inp = (const float*)d_in[0];   // "input"
    const float* tgt = (const float*)d_in[1];   // "target"
    float* out = (float*)d_out;

    double*   partials = (double*)d_ws;                        // 32 KB (fully written)
    uint64_t* mask0 = (uint64_t*)((char*)d_ws + 64 * 1024);    // 2 MB
    uint64_t* mask1 = mask0 + NWORDS;                          // 2 MB

    mask_xdil<<<NWORDS / 16, 256, 0, stream>>>(tgt, mask0);    // 16384 blocks, 4 rows each
    yz_dil<<<dim3(HH / 16, DD / 16, BB * WPR), 256, 0, stream>>>(mask0, mask1);
    reduce_loss<<<RBLOCKS, 256, 0, stream>>>(inp, tgt, mask1, partials);
    finalize<<<1, 1024, 0, stream>>>(partials, out);
}